// Round 3
// baseline (226.369 us; speedup 1.0000x reference)
//
#include <hip/hip_runtime.h>
#include <stdint.h>

#define B_DIM 8
#define N_DIM 2048
#define F_DIM 128
#define LN_EPS 1e-5f

typedef __attribute__((ext_vector_type(8))) short short8;
typedef __attribute__((ext_vector_type(4))) float floatx4;

// full RNE fp32 -> bf16
__device__ __forceinline__ ushort f2bf(float f) {
    union { float f; uint32_t u; } c;
    c.f = f;
    uint32_t u = c.u;
    return (ushort)((u + 0x7FFFu + ((u >> 16) & 1u)) >> 16);
}

// fast round-half-up pack of two fp32 -> packed bf16x2
__device__ __forceinline__ uint32_t pk2bf(float a, float b) {
    union { float f; uint32_t u; } x, y;
    x.f = a; y.f = b;
    return ((x.u + 0x8000u) >> 16) | ((y.u + 0x8000u) & 0xFFFF0000u);
}

__device__ __forceinline__ short8 pack8(float4 lo, float4 hi) {
    union { uint32_t u[4]; short8 s; } r;
    r.u[0] = pk2bf(lo.x, lo.y);
    r.u[1] = pk2bf(lo.z, lo.w);
    r.u[2] = pk2bf(hi.x, hi.y);
    r.u[3] = pk2bf(hi.z, hi.w);
    return r.s;
}

__device__ __forceinline__ void load_lds16(const ushort* g, ushort* l) {
    __builtin_amdgcn_global_load_lds(
        (const __attribute__((address_space(1))) void*)g,
        (__attribute__((address_space(3))) void*)l,
        16, 0, 0);
}

// ---------------------------------------------------------------------------
// Kernel 1: X (B, K=2048, F=128) fp32 -> Xt (B, F=128, K=2048) bf16.
// ---------------------------------------------------------------------------
__global__ __launch_bounds__(256) void k_transpose(const float* __restrict__ X,
                                                   ushort* __restrict__ Xt) {
    __shared__ ushort tile[64 * 65];
    const int t = threadIdx.x;
    const int b = blockIdx.z;
    const int k0 = blockIdx.x * 64;
    const int f0 = blockIdx.y * 64;

#pragma unroll
    for (int p = 0; p < 2; ++p) {
        int idx = p * 256 + t;
        int kk = idx >> 3;
        int ff = (idx & 7) * 8;
        const float* src = X + (((size_t)b * N_DIM) + k0 + kk) * F_DIM + f0 + ff;
        float4 v0 = *(const float4*)(src);
        float4 v1 = *(const float4*)(src + 4);
        ushort* d = tile + kk * 65 + ff;
        d[0] = f2bf(v0.x); d[1] = f2bf(v0.y); d[2] = f2bf(v0.z); d[3] = f2bf(v0.w);
        d[4] = f2bf(v1.x); d[5] = f2bf(v1.y); d[6] = f2bf(v1.z); d[7] = f2bf(v1.w);
    }
    __syncthreads();

    union U { uint4 v; ushort s[8]; };
#pragma unroll
    for (int p = 0; p < 2; ++p) {
        int idx = p * 256 + t;
        int f2 = idx >> 3;
        int kk2 = (idx & 7) * 8;
        U u;
#pragma unroll
        for (int j = 0; j < 8; ++j) u.s[j] = tile[(kk2 + j) * 65 + f2];
        *(uint4*)(Xt + (((size_t)b * F_DIM) + f0 + f2) * N_DIM + k0 + kk2) = u.v;
    }
}

// ---------------------------------------------------------------------------
// Kernel 2 (fused): H = A@X (bf16 MFMA), P = H@W^T + b, LN(128), ReLU.
//
// v3: BM=16, BN=128, BK=64 -> LDS 36 KB -> 4 blocks/CU (was 2).  Grid 1024
// blocks = 4 x 256 CUs.  4 independent barrier groups per CU cover each
// other's stage/drain bubbles (round-1 lesson: intra-block pipelining is
// neutral; inter-block overlap is the lever).  Same proven XOR swizzles,
// counted-vmcnt pipeline (4 glds drained, 1 A-load left in flight), and
// epilogue, adapted to 16 rows.  __launch_bounds__(256,4) caps VGPR <= 128
// so 16 waves/CU actually materialize.
// ---------------------------------------------------------------------------
__global__ __launch_bounds__(256, 4) void k_fused(const float* __restrict__ A,
                                                  const ushort* __restrict__ Xt,
                                                  const float* __restrict__ W,
                                                  const float* __restrict__ bias,
                                                  const float* __restrict__ gamma,
                                                  const float* __restrict__ beta,
                                                  float* __restrict__ out) {
    __shared__ __align__(16) char smem[36864];
    ushort* const As0 = (ushort*)smem;                    // 16x64 bf16 = 2 KB
    ushort* const As1 = (ushort*)(smem + 2048);
    ushort* const Bs0 = (ushort*)(smem + 4096);           // 128x64 bf16 = 16 KB
    ushort* const Bs1 = (ushort*)(smem + 4096 + 16384);
    // epilogue aliases (valid after the post-K-loop __syncthreads):
    ushort* const Ht = (ushort*)smem;                     // 16*136 bf16 = 4352 B
    float (*const Pt)[132] = (float(*)[132])(smem + 9216);  // 16*132 f32 = 8448 B

    const int t = threadIdx.x;
    const int lane = t & 63;
    const int w = t >> 6;            // wave 0..3
    const int q = lane >> 4;         // 0..3
    const int mr = lane & 15;        // 0..15

    const int bid = blockIdx.x;
    const int bb = bid & 7;          // batch -> XCD affinity (L2 keeps Xt slice)
    const int m0 = (bid >> 3) * 16;  // M-tile origin (128 m-tiles x 8 batches)

    const float* Ab = A + ((size_t)bb * N_DIM + m0) * N_DIM;
    const ushort* Xb = Xt + (size_t)bb * F_DIM * N_DIM;

    // A staging: thread t -> row (t>>4), one float4 at k=(t&15)*4 (coalesced).
    // Source half-chunk j=t&15: chunk c=j>>1 stored at (c ^ (row&7)), half j&1.
    const int arow = t >> 4;
    const float* a_src = Ab + (size_t)arow * N_DIM + (t & 15) * 4;
    const int a_off = arow * 64 + (((t & 15) >> 1) ^ (arow & 7)) * 8 + (t & 1) * 4;

    // B staging: 4 glds chunks per thread; LDS slot c = p*256+t (contiguous
    // per wave as glds requires), source chunk kc = (c&7) ^ (n&7), n = c>>3.
    const ushort* b_src[4];
    int b_off[4];
#pragma unroll
    for (int p = 0; p < 4; ++p) {
        int c = p * 256 + t;
        int n = c >> 3;
        int kc = (c & 7) ^ (n & 7);
        b_src[p] = Xb + (size_t)n * N_DIM + kc * 8;
        b_off[p] = c * 8;
    }

    floatx4 acc[2];
    acc[0] = (floatx4){0.f, 0.f, 0.f, 0.f};
    acc[1] = (floatx4){0.f, 0.f, 0.f, 0.f};

    auto stageB = [&](int k0, ushort* Bn) {
#pragma unroll
        for (int p = 0; p < 4; ++p) load_lds16(b_src[p] + k0, Bn + b_off[p]);
    };
    auto packA = [&](float4 v, ushort* An) {
        union { uint32_t u[2]; } r;
        r.u[0] = pk2bf(v.x, v.y);
        r.u[1] = pk2bf(v.z, v.w);
        *(uint2*)(An + a_off) = *(const uint2*)r.u;
    };
    auto compute = [&](const ushort* Ac, const ushort* Bc) {
#pragma unroll
        for (int ks = 0; ks < 2; ++ks) {
            short8 af = *(const short8*)(Ac + mr * 64 +
                                         (((ks * 4 + q) ^ (mr & 7)) * 8));
#pragma unroll
            for (int j = 0; j < 2; ++j) {
                int n = w * 32 + j * 16 + mr;
                short8 bfr = *(const short8*)(Bc + n * 64 +
                                              (((ks * 4 + q) ^ (n & 7)) * 8));
                acc[j] = __builtin_amdgcn_mfma_f32_16x16x32_bf16(af, bfr, acc[j],
                                                                 0, 0, 0);
            }
        }
    };

    float4 r0, r1;

    // ---- prologue: tile 0 -> buf0; A(1) load left in flight across barrier
    r0 = *(const float4*)(a_src);
    stageB(0, Bs0);
    packA(r0, As0);
    __builtin_amdgcn_sched_barrier(0);  // pin: A(1) issued after glds
    r1 = *(const float4*)(a_src + 64);
    asm volatile("s_waitcnt vmcnt(1) lgkmcnt(0)" ::: "memory");
    __builtin_amdgcn_s_barrier();

    // ---- main loop: tiles 0..29 (unroll x2: even->buf0, odd->buf1)
#pragma unroll 1
    for (int tt = 0; tt < 30; tt += 2) {
        const int k0 = tt * 64;
        // even sub-iter: compute tile tt (buf0)
        stageB(k0 + 64, Bs1);
        __builtin_amdgcn_sched_barrier(0);
        r0 = *(const float4*)(a_src + k0 + 128);
        compute(As0, Bs0);
        packA(r1, As1);
        asm volatile("s_waitcnt vmcnt(1) lgkmcnt(0)" ::: "memory");
        __builtin_amdgcn_s_barrier();

        // odd sub-iter: compute tile tt+1 (buf1)
        stageB(k0 + 128, Bs0);
        __builtin_amdgcn_sched_barrier(0);
        r1 = *(const float4*)(a_src + k0 + 192);
        compute(As1, Bs1);
        packA(r0, As0);
        asm volatile("s_waitcnt vmcnt(1) lgkmcnt(0)" ::: "memory");
        __builtin_amdgcn_s_barrier();
    }

    // ---- tail: tile 30 (buf0) with last stage, then tile 31 (buf1)
    stageB(31 * 64, Bs1);
    compute(As0, Bs0);
    packA(r1, As1);
    asm volatile("s_waitcnt vmcnt(0) lgkmcnt(0)" ::: "memory");
    __builtin_amdgcn_s_barrier();

    compute(As1, Bs1);
    __syncthreads();  // full drain before epilogue aliases the stage buffers

    // ---- scatter H tile (bf16). D layout: col=lane&15, row=q*4+reg [m89]
#pragma unroll
    for (int j = 0; j < 2; ++j) {
        int col = w * 32 + j * 16 + mr;
#pragma unroll
        for (int r = 0; r < 4; ++r)
            Ht[(q * 4 + r) * 136 + col] = f2bf(acc[j][r]);
    }
    __syncthreads();

    // ---- P[16x128] = Ht @ W^T  (W fp32 from global, L1/L2-hot)
    floatx4 p[2];
    p[0] = (floatx4){0.f, 0.f, 0.f, 0.f};
    p[1] = (floatx4){0.f, 0.f, 0.f, 0.f};

#pragma unroll
    for (int ks = 0; ks < 4; ++ks) {
        short8 ha = *(const short8*)(Ht + mr * 136 + ks * 32 + q * 8);
#pragma unroll
        for (int j = 0; j < 2; ++j) {
            const float* wp = W + (w * 32 + j * 16 + mr) * F_DIM + ks * 32 + q * 8;
            short8 wb = pack8(((const float4*)wp)[0], ((const float4*)wp)[1]);
            p[j] = __builtin_amdgcn_mfma_f32_16x16x32_bf16(ha, wb, p[j], 0, 0, 0);
        }
    }

    // ---- bias add, scatter P (fp32) for row-major LN
#pragma unroll
    for (int j = 0; j < 2; ++j) {
        int col = w * 32 + j * 16 + mr;
        float bcol = bias[col];
#pragma unroll
        for (int r = 0; r < 4; ++r)
            Pt[q * 4 + r][col] = p[j][r] + bcol;
    }
    __syncthreads();

    // ---- LayerNorm + ReLU: 16 lanes per row, 8 values each
    const int row = t >> 4;
    const int seg = t & 15;
    float v[8];
    float s = 0.f, s2 = 0.f;
#pragma unroll
    for (int u = 0; u < 8; ++u) {
        v[u] = Pt[row][seg * 8 + u];
        s += v[u];
        s2 += v[u] * v[u];
    }
    s += __shfl_xor(s, 1);  s2 += __shfl_xor(s2, 1);
    s += __shfl_xor(s, 2);  s2 += __shfl_xor(s2, 2);
    s += __shfl_xor(s, 4);  s2 += __shfl_xor(s2, 4);
    s += __shfl_xor(s, 8);  s2 += __shfl_xor(s2, 8);
    float mu = s * (1.0f / 128.0f);
    float var = s2 * (1.0f / 128.0f) - mu * mu;
    float rs = rsqrtf(var + LN_EPS);

    float4 o[2];
    float* of = (float*)o;
#pragma unroll
    for (int u = 0; u < 8; ++u) {
        int d = seg * 8 + u;
        float y = (v[u] - mu) * rs * gamma[d] + beta[d];
        of[u] = fmaxf(y, 0.0f);
    }
    float4* dst = (float4*)(out + ((size_t)bb * N_DIM + m0 + row) * F_DIM + seg * 8);
    dst[0] = o[0]; dst[1] = o[1];
}

// ---------------------------------------------------------------------------
extern "C" void kernel_launch(void* const* d_in, const int* in_sizes, int n_in,
                              void* d_out, int out_size, void* d_ws, size_t ws_size,
                              hipStream_t stream) {
    const float* A     = (const float*)d_in[0];
    const float* X     = (const float*)d_in[1];
    const float* W     = (const float*)d_in[2];
    const float* bias  = (const float*)d_in[3];
    const float* gamma = (const float*)d_in[4];
    const float* beta  = (const float*)d_in[5];
    float* out = (float*)d_out;

    ushort* Xt = (ushort*)d_ws;  // 4 MB bf16

    k_transpose<<<dim3(32, 2, 8), 256, 0, stream>>>(X, Xt);
    k_fused<<<dim3(1024), 256, 0, stream>>>(A, Xt, W, bias, gamma, beta, out);
}